// Round 2
// baseline (82.714 us; speedup 1.0000x reference)
//
#include <hip/hip_runtime.h>

#define NBOX 64
#define NCLS 81
#define NCH  86   // 4 reg + 1 cent + 81 cls

// Levels (IMAGE_SIZE=1024, strides 8/16/32/64/128), 2 cells per thread:
//   lvl  H    ps        th_lo      th_hi    base (elems)   blocks(256 thr)
//   0    128  1/128     .0078125   .0625    0              256
//   1    64   1/64      .0625      .125     11272192       64
//   2    32   1/32      .125       .25      14090240       16
//   3    16   1/16      .25        .5       14794752       4
//   4    8    1/8       .5         1.0      14970880       1
// total 341 blocks, all full; every block is level-pure.

__global__ __launch_bounds__(256) void fcos_mapper(
    const float* __restrict__ boxes,   // [8][64][4]
    const int*   __restrict__ labels,  // [8][64]
    float*       __restrict__ out)     // 15,014,912 f32
{
    const int tid = threadIdx.x;
    const int bid = blockIdx.x;

    __shared__ float4 sbx[8][NBOX];
    __shared__ int    sl [8][NBOX];
    __shared__ float  sa [4][NBOX];

    // ---- stable descending-area sort of all 8 batches (2 passes x 4) ----
    {
        const int slot = tid >> 6;     // 0..3
        const int box  = tid & 63;
        #pragma unroll
        for (int pass = 0; pass < 2; ++pass) {
            const int bb = pass * 4 + slot;
            const float4 bx = reinterpret_cast<const float4*>(boxes)[bb * NBOX + box];
            const float area = (bx.z - bx.x) * (bx.w - bx.y);
            sa[slot][box] = area;
            __syncthreads();
            int rank = 0;
            for (int j = 0; j < NBOX; ++j) {
                const float aj = sa[slot][j];
                rank += ((aj > area) || (aj == area && j < box)) ? 1 : 0;
            }
            sbx[bb][rank] = bx;
            sl [bb][rank] = labels[bb * NBOX + box];
            __syncthreads();
        }
    }

    // ---- level constants (uniform per block) ----
    int rel, logH; float ps, tlo, thi; size_t base0;
    if (bid < 256)      { rel = bid;       logH = 7; ps = 0.0078125f; tlo = 0.0078125f; thi = 0.0625f; base0 = 0; }
    else if (bid < 320) { rel = bid - 256; logH = 6; ps = 0.015625f;  tlo = 0.0625f;    thi = 0.125f;  base0 = 11272192; }
    else if (bid < 336) { rel = bid - 320; logH = 5; ps = 0.03125f;   tlo = 0.125f;     thi = 0.25f;   base0 = 14090240; }
    else if (bid < 340) { rel = bid - 336; logH = 4; ps = 0.0625f;    tlo = 0.25f;      thi = 0.5f;    base0 = 14794752; }
    else                { rel = bid - 340; logH = 3; ps = 0.125f;     tlo = 0.5f;       thi = 1.0f;    base0 = 14970880; }

    const int H    = 1 << logH;
    const int HW   = 1 << (2 * logH);
    const int lppp = 2 * logH - 1;                 // log2(pairs per batch-plane)
    const int p    = (rel << 8) + tid;             // pair index within level
    const int b    = p >> lppp;
    const int cell = (p & ((1 << lppp) - 1)) << 1; // first of 2 contiguous cells (same row)
    const int y    = cell >> logH;
    const int x0   = cell & (H - 1);

    const float gy  = ((float)y  + 0.5f) * ps;
    const float gx0 = ((float)x0 + 0.5f) * ps;
    const float gx1 = gx0 + ps;

    // ---- scan sorted boxes: last match per cell, fg_any per cell ----
    const float4* bxp = sbx[b];
    int  win0 = -1, win1 = -1;
    bool fga0 = false, fga1 = false;
    #pragma unroll 8
    for (int n = 0; n < NBOX; ++n) {
        const float4 bb = bxp[n];                  // LDS broadcast b128
        const float t    = gy - bb.y;
        const float d    = bb.w - gy;
        const float tbmn = fminf(t, d);
        const float tbmx = fmaxf(t, d);
        {
            const float l  = gx0 - bb.x;
            const float r  = bb.z - gx0;
            const float mn = fminf(tbmn, fminf(l, r));
            const float mx = fmaxf(tbmx, fmaxf(l, r));
            const bool  fg = (mn >= 0.0f);
            fga0 = fga0 || fg;
            if (fg && (mx > tlo) && (mx <= thi)) win0 = n;
        }
        {
            const float l  = gx1 - bb.x;
            const float r  = bb.z - gx1;
            const float mn = fminf(tbmn, fminf(l, r));
            const float mx = fmaxf(tbmx, fmaxf(l, r));
            const bool  fg = (mn >= 0.0f);
            fga1 = fga1 || fg;
            if (fg && (mx > tlo) && (mx <= thi)) win1 = n;
        }
    }

    // ---- winner values per cell ----
    float l0=0.f, t0=0.f, r0=0.f, d0=0.f, c0=0.f;
    float l1=0.f, t1=0.f, r1=0.f, d1=0.f, c1=0.f;
    int tg0, tg1;
    if (win0 >= 0) {
        const float4 wb = bxp[win0];
        l0 = gx0 - wb.x; t0 = gy - wb.y; r0 = wb.z - gx0; d0 = wb.w - gy;
        const float dx = fminf(l0, r0), Dx = fmaxf(l0, r0);
        const float dy = fminf(t0, d0), Dy = fmaxf(t0, d0);
        const float arg = (dx / (Dx != 0.f ? Dx : 1.f)) * (dy / (Dy != 0.f ? Dy : 1.f));
        c0 = (arg > 0.f) ? sqrtf(arg) : 0.f;
        tg0 = sl[b][win0];
    } else tg0 = fga0 ? -1 : 0;
    if (win1 >= 0) {
        const float4 wb = bxp[win1];
        l1 = gx1 - wb.x; t1 = gy - wb.y; r1 = wb.z - gx1; d1 = wb.w - gy;
        const float dx = fminf(l1, r1), Dx = fmaxf(l1, r1);
        const float dy = fminf(t1, d1), Dy = fmaxf(t1, d1);
        const float arg = (dx / (Dx != 0.f ? Dx : 1.f)) * (dy / (Dy != 0.f ? Dy : 1.f));
        c1 = (arg > 0.f) ? sqrtf(arg) : 0.f;
        tg1 = sl[b][win1];
    } else tg1 = fga1 ? -1 : 0;

    // ---- stores: 5 value channels + 81 zero channels (float2), then scatter 1.0 ----
    float* po = out + base0 + (size_t)b * NCH * HW + cell;
    *reinterpret_cast<float2*>(po + 0 * (size_t)HW) = make_float2(l0, l1);
    *reinterpret_cast<float2*>(po + 1 * (size_t)HW) = make_float2(t0, t1);
    *reinterpret_cast<float2*>(po + 2 * (size_t)HW) = make_float2(r0, r1);
    *reinterpret_cast<float2*>(po + 3 * (size_t)HW) = make_float2(d0, d1);
    *reinterpret_cast<float2*>(po + 4 * (size_t)HW) = make_float2(c0, c1);
    const float2 z2 = make_float2(0.f, 0.f);
    #pragma unroll
    for (int c = 0; c < NCLS; ++c)
        *reinterpret_cast<float2*>(po + (size_t)(5 + c) * HW) = z2;
    if (tg0 >= 0) po[(size_t)(5 + tg0) * HW]     = 1.0f;
    if (tg1 >= 0) po[(size_t)(5 + tg1) * HW + 1] = 1.0f;
}

extern "C" void kernel_launch(void* const* d_in, const int* in_sizes, int n_in,
                              void* d_out, int out_size, void* d_ws, size_t ws_size,
                              hipStream_t stream) {
    const float* boxes  = (const float*)d_in[0];
    const int*   labels = (const int*)d_in[1];
    float*       out    = (float*)d_out;
    fcos_mapper<<<341, 256, 0, stream>>>(boxes, labels, out);
}